// Round 1
// baseline (888.118 us; speedup 1.0000x reference)
//
#include <hip/hip_runtime.h>

#define RNN_T 2048
#define RNN_B 4096

// tanh with pre-scaled argument: zs = 2*log2(e)*z ; tanh(z) = 1 - 2/(1 + 2^zs)
__device__ __forceinline__ float tanh_pre(float zs) {
    float e = __builtin_amdgcn_exp2f(zs);
    float r = __builtin_amdgcn_rcpf(e + 1.0f);
    return fmaf(-2.0f, r, 1.0f);
}

template <int U>
__device__ __forceinline__ void rnn1_step(const float (&xs)[20], float (&h)[9],
                                          const float (&W1)[9][5],
                                          const float (&W2)[9][9],
                                          const float (&bb)[9]) {
    float z[9];
#pragma unroll
    for (int i = 0; i < 9; ++i) {
        float acc = bb[i];
#pragma unroll
        for (int d = 0; d < 5; ++d) acc = fmaf(W1[i][d], xs[U * 5 + d], acc);
#pragma unroll
        for (int k = 0; k < 9; ++k) acc = fmaf(W2[i][k], h[k], acc);
        z[i] = acc;
    }
#pragma unroll
    for (int i = 0; i < 9; ++i) h[i] = tanh_pre(z[i]);
}

__global__ __launch_bounds__(64) void rnn1_kernel(
    const float* __restrict__ x,
    const float* __restrict__ w_ih_f, const float* __restrict__ w_hh_f,
    const float* __restrict__ b_ih_f, const float* __restrict__ b_hh_f,
    const float* __restrict__ w_ih_b, const float* __restrict__ w_hh_b,
    const float* __restrict__ b_ih_b, const float* __restrict__ b_hh_b,
    float* __restrict__ y)
{
    const float SC = 2.8853900817779268f; // 2*log2(e)
    const int gid = blockIdx.x * 64 + threadIdx.x;   // 0..8191
    const int dir = gid >> 12;                       // wave-uniform (64 blocks/dir)
    const int b   = gid & (RNN_B - 1);

    const float* __restrict__ wih = dir ? w_ih_b : w_ih_f;
    const float* __restrict__ whh = dir ? w_hh_b : w_hh_f;
    const float* __restrict__ bih = dir ? b_ih_b : b_ih_f;
    const float* __restrict__ bhh = dir ? b_hh_b : b_hh_f;

    float W1[9][5], W2[9][9], bb[9];
#pragma unroll
    for (int i = 0; i < 9; ++i) {
#pragma unroll
        for (int d = 0; d < 5; ++d) W1[i][d] = wih[i * 5 + d] * SC;
#pragma unroll
        for (int k = 0; k < 9; ++k) W2[i][k] = whh[i * 9 + k] * SC;
        bb[i] = (bih[i] + bhh[i]) * SC;
    }

    float h[9];
#pragma unroll
    for (int i = 0; i < 9; ++i) h[i] = 0.0f;

    const float* xp = x + (size_t)b * (RNN_T * 5);
    const int NB = RNN_T / 4;   // 512 blocks of 4 timesteps (20 floats = 5 float4)

    float4 buf[5];
    {
        const int bo = dir ? (NB - 1) : 0;
        const float4* q = (const float4*)(xp + bo * 20);
#pragma unroll
        for (int v = 0; v < 5; ++v) buf[v] = q[v];
    }

    for (int blk = 0; blk < NB; ++blk) {
        float xs[20];
#pragma unroll
        for (int v = 0; v < 5; ++v) {
            xs[v * 4 + 0] = buf[v].x; xs[v * 4 + 1] = buf[v].y;
            xs[v * 4 + 2] = buf[v].z; xs[v * 4 + 3] = buf[v].w;
        }
        if (blk + 1 < NB) {           // prefetch next 4-step block
            const int bo = dir ? (NB - 2 - blk) : (blk + 1);
            const float4* q = (const float4*)(xp + bo * 20);
#pragma unroll
            for (int v = 0; v < 5; ++v) buf[v] = q[v];
        }
        if (dir == 0) {
            rnn1_step<0>(xs, h, W1, W2, bb);
            rnn1_step<1>(xs, h, W1, W2, bb);
            rnn1_step<2>(xs, h, W1, W2, bb);
            rnn1_step<3>(xs, h, W1, W2, bb);
        } else {
            rnn1_step<3>(xs, h, W1, W2, bb);
            rnn1_step<2>(xs, h, W1, W2, bb);
            rnn1_step<1>(xs, h, W1, W2, bb);
            rnn1_step<0>(xs, h, W1, W2, bb);
        }
    }

#pragma unroll
    for (int i = 0; i < 9; ++i) y[b * 18 + dir * 9 + i] = h[i];
}

__global__ __launch_bounds__(256) void rnn2_kernel(
    const float* __restrict__ y,
    const float* __restrict__ w_ih2, const float* __restrict__ w_hh2,
    const float* __restrict__ b_ih2, const float* __restrict__ b_hh2,
    const float* __restrict__ w_out, const float* __restrict__ b_out,
    float* __restrict__ out)
{
    __shared__ float hist[8][25][32];   // 25.6 KB
    const float SC = 2.8853900817779268f;
    const int bl = threadIdx.x >> 5;    // 0..7 local batch
    const int i  = threadIdx.x & 31;    // component
    const int b  = blockIdx.x * 8 + bl;

    float wr[32];
#pragma unroll
    for (int k = 0; k < 32; ++k) wr[k] = w_hh2[i * 32 + k] * SC;
    const float bias = (b_ih2[i] + b_hh2[i]) * SC;

    // t = 0: input is y, prev hidden is 0
    const float* yb = y + b * 18;
    float z = bias;
#pragma unroll
    for (int k = 0; k < 18; ++k) z = fmaf(w_ih2[i * 18 + k] * SC, yb[k], z);
    hist[bl][0][i] = tanh_pre(z);
    __syncthreads();

    for (int t = 1; t < 25; ++t) {
        float zz = bias;
#pragma unroll
        for (int k = 0; k < 32; ++k) zz = fmaf(wr[k], hist[bl][t - 1][k], zz);
        hist[bl][t][i] = tanh_pre(zz);
        __syncthreads();
    }

    // epilogue: out[b][t][o] = dot(w_out[o], hist[b][t]) + b_out[o]
    for (int e = threadIdx.x; e < 600; e += 256) {
        const int o  = e % 3;
        const int t  = (e / 3) % 25;
        const int b2 = e / 75;
        float acc = b_out[o];
#pragma unroll
        for (int k = 0; k < 32; ++k) acc = fmaf(w_out[o * 32 + k], hist[b2][t][k], acc);
        out[((size_t)(blockIdx.x * 8 + b2) * 25 + t) * 3 + o] = acc;
    }
}

extern "C" void kernel_launch(void* const* d_in, const int* in_sizes, int n_in,
                              void* d_out, int out_size, void* d_ws, size_t ws_size,
                              hipStream_t stream) {
    const float* x      = (const float*)d_in[0];
    const float* w_ih_f = (const float*)d_in[1];
    const float* w_hh_f = (const float*)d_in[2];
    const float* b_ih_f = (const float*)d_in[3];
    const float* b_hh_f = (const float*)d_in[4];
    const float* w_ih_b = (const float*)d_in[5];
    const float* w_hh_b = (const float*)d_in[6];
    const float* b_ih_b = (const float*)d_in[7];
    const float* b_hh_b = (const float*)d_in[8];
    const float* w_ih2  = (const float*)d_in[9];
    const float* w_hh2  = (const float*)d_in[10];
    const float* b_ih2  = (const float*)d_in[11];
    const float* b_hh2  = (const float*)d_in[12];
    const float* w_out  = (const float*)d_in[13];
    const float* b_out  = (const float*)d_in[14];

    float* y = (float*)d_ws;                 // [B][18] intermediate

    rnn1_kernel<<<dim3(128), dim3(64), 0, stream>>>(
        x, w_ih_f, w_hh_f, b_ih_f, b_hh_f,
        w_ih_b, w_hh_b, b_ih_b, b_hh_b, y);

    rnn2_kernel<<<dim3(RNN_B / 8), dim3(256), 0, stream>>>(
        y, w_ih2, w_hh2, b_ih2, b_hh2, w_out, b_out, (float*)d_out);
}

// Round 2
// 799.449 us; speedup vs baseline: 1.1109x; 1.1109x over previous
//
#include <hip/hip_runtime.h>

#define RNN_T 2048
#define RNN_B 4096
#define BLK 8              // timesteps per x block (40 floats = 10 float4)
#define NBLK (RNN_T / BLK) // 256

// tanh with pre-scaled argument: zs = 2*log2(e)*z ; tanh(z) = 1 - 2/(1 + 2^zs)
__device__ __forceinline__ float tanh_pre(float zs) {
    float e = __builtin_amdgcn_exp2f(zs);
    float r = __builtin_amdgcn_rcpf(e + 1.0f);
    return fmaf(-2.0f, r, 1.0f);
}

// Broadcast lane (group16_base | K)'s value to all 16 lanes of the group.
// ds_swizzle BitMode: src = ((lane & and_mask) | or_mask) ^ xor_mask,
// offset = (xor<<10)|(or<<5)|and  ->  and=16, or=K, xor=0.
template <int K>
__device__ __forceinline__ float bcast16(float v) {
    return __int_as_float(__builtin_amdgcn_ds_swizzle(__float_as_int(v), (K << 5) | 16));
}

template <int IDX>
__device__ __forceinline__ float getf(const float4 (&b)[10]) {
    constexpr int q = IDX >> 2, r = IDX & 3;
    if constexpr (r == 0) return b[q].x;
    else if constexpr (r == 1) return b[q].y;
    else if constexpr (r == 2) return b[q].z;
    else return b[q].w;
}

// One timestep: lane holds h[i]; gathers h[0..8] from lanes 0..8 of its group.
template <int U>
__device__ __forceinline__ void step16(const float4 (&buf)[10], float& h,
                                       const float (&W1)[5], const float (&W2)[9],
                                       const float bb) {
    float h0 = bcast16<0>(h), h1 = bcast16<1>(h), h2 = bcast16<2>(h);
    float h3 = bcast16<3>(h), h4 = bcast16<4>(h), h5 = bcast16<5>(h);
    float h6 = bcast16<6>(h), h7 = bcast16<7>(h), h8 = bcast16<8>(h);
    // x part (independent of broadcasts -> fills swizzle latency)
    float a0 = fmaf(W1[0], getf<U * 5 + 0>(buf), bb);
    a0 = fmaf(W1[1], getf<U * 5 + 1>(buf), a0);
    a0 = fmaf(W1[2], getf<U * 5 + 2>(buf), a0);
    a0 = fmaf(W1[3], getf<U * 5 + 3>(buf), a0);
    a0 = fmaf(W1[4], getf<U * 5 + 4>(buf), a0);
    // h part, 3 accumulators to cut dependency depth
    float a1 = W2[0] * h0;
    a1 = fmaf(W2[1], h1, a1);
    a1 = fmaf(W2[2], h2, a1);
    float a2 = W2[3] * h3;
    a2 = fmaf(W2[4], h4, a2);
    a2 = fmaf(W2[5], h5, a2);
    a0 = fmaf(W2[6], h6, a0);
    a1 = fmaf(W2[7], h7, a1);
    a2 = fmaf(W2[8], h8, a2);
    h = tanh_pre((a0 + a1) + a2);
}

__device__ __forceinline__ void loadblk(float4 (&buf)[10], const float* xp, int phys) {
    const float4* q = (const float4*)(xp + phys * (BLK * 5));
#pragma unroll
    for (int v = 0; v < 10; ++v) buf[v] = q[v];
}

template <bool FWD>
__device__ __forceinline__ void proc8(const float4 (&buf)[10], float& h,
                                      const float (&W1)[5], const float (&W2)[9],
                                      const float bb) {
    if constexpr (FWD) {
        step16<0>(buf, h, W1, W2, bb); step16<1>(buf, h, W1, W2, bb);
        step16<2>(buf, h, W1, W2, bb); step16<3>(buf, h, W1, W2, bb);
        step16<4>(buf, h, W1, W2, bb); step16<5>(buf, h, W1, W2, bb);
        step16<6>(buf, h, W1, W2, bb); step16<7>(buf, h, W1, W2, bb);
    } else {
        step16<7>(buf, h, W1, W2, bb); step16<6>(buf, h, W1, W2, bb);
        step16<5>(buf, h, W1, W2, bb); step16<4>(buf, h, W1, W2, bb);
        step16<3>(buf, h, W1, W2, bb); step16<2>(buf, h, W1, W2, bb);
        step16<1>(buf, h, W1, W2, bb); step16<0>(buf, h, W1, W2, bb);
    }
}

template <bool FWD>
__device__ __forceinline__ int physOf(int i) {
    if constexpr (FWD) return (i < NBLK - 1) ? i : (NBLK - 1);
    else { int p = NBLK - 1 - i; return (p > 0) ? p : 0; }
}

template <bool FWD>
__device__ __forceinline__ float run_chain(const float* xp, const float (&W1)[5],
                                           const float (&W2)[9], const float bb) {
    float4 A[10], B[10], C[10], D[10];
    float h = 0.0f;
    loadblk(A, xp, physOf<FWD>(0));
    loadblk(B, xp, physOf<FWD>(1));
    loadblk(C, xp, physOf<FWD>(2));
    for (int i = 0; i < NBLK; i += 4) {
        loadblk(D, xp, physOf<FWD>(i + 3));
        proc8<FWD>(A, h, W1, W2, bb);
        loadblk(A, xp, physOf<FWD>(i + 4));
        proc8<FWD>(B, h, W1, W2, bb);
        loadblk(B, xp, physOf<FWD>(i + 5));
        proc8<FWD>(C, h, W1, W2, bb);
        loadblk(C, xp, physOf<FWD>(i + 6));
        proc8<FWD>(D, h, W1, W2, bb);
    }
    return h;
}

// 16 lanes per chain: lane i in [0,9) owns h[i]; lanes 9-15 duplicate i=8.
// 512 blocks x 256 threads = 2048 waves = 2 waves/SIMD machine-wide.
__global__ __launch_bounds__(256, 2) void rnn1_kernel(
    const float* __restrict__ x,
    const float* __restrict__ w_ih_f, const float* __restrict__ w_hh_f,
    const float* __restrict__ b_ih_f, const float* __restrict__ b_hh_f,
    const float* __restrict__ w_ih_b, const float* __restrict__ w_hh_b,
    const float* __restrict__ b_ih_b, const float* __restrict__ b_hh_b,
    float* __restrict__ y)
{
    const float SC = 2.8853900817779268f; // 2*log2(e)
    const int tid    = threadIdx.x;
    const int group  = tid >> 4;
    const int lane16 = tid & 15;
    const int chain  = blockIdx.x * 16 + group;   // 0..8191
    const int b      = chain & (RNN_B - 1);
    const int dir    = chain >> 12;               // uniform per block
    const int i      = (lane16 < 9) ? lane16 : 8;

    const float* __restrict__ wih = dir ? w_ih_b : w_ih_f;
    const float* __restrict__ whh = dir ? w_hh_b : w_hh_f;
    const float* __restrict__ bih = dir ? b_ih_b : b_ih_f;
    const float* __restrict__ bhh = dir ? b_hh_b : b_hh_f;

    float W1[5], W2[9];
#pragma unroll
    for (int d = 0; d < 5; ++d) W1[d] = wih[i * 5 + d] * SC;
#pragma unroll
    for (int k = 0; k < 9; ++k) W2[k] = whh[i * 9 + k] * SC;
    const float bb = (bih[i] + bhh[i]) * SC;

    const float* xp = x + (size_t)b * (RNN_T * 5);
    float h = dir ? run_chain<false>(xp, W1, W2, bb)
                  : run_chain<true>(xp, W1, W2, bb);

    if (lane16 < 9) y[b * 18 + dir * 9 + lane16] = h;
}

__global__ __launch_bounds__(256) void rnn2_kernel(
    const float* __restrict__ y,
    const float* __restrict__ w_ih2, const float* __restrict__ w_hh2,
    const float* __restrict__ b_ih2, const float* __restrict__ b_hh2,
    const float* __restrict__ w_out, const float* __restrict__ b_out,
    float* __restrict__ out)
{
    __shared__ float hist[8][25][32];   // 25.6 KB
    const float SC = 2.8853900817779268f;
    const int bl = threadIdx.x >> 5;    // 0..7 local batch
    const int i  = threadIdx.x & 31;    // component
    const int b  = blockIdx.x * 8 + bl;

    float wr[32];
#pragma unroll
    for (int k = 0; k < 32; ++k) wr[k] = w_hh2[i * 32 + k] * SC;
    const float bias = (b_ih2[i] + b_hh2[i]) * SC;

    // t = 0: input is y, prev hidden is 0
    const float* yb = y + b * 18;
    float z = bias;
#pragma unroll
    for (int k = 0; k < 18; ++k) z = fmaf(w_ih2[i * 18 + k] * SC, yb[k], z);
    hist[bl][0][i] = tanh_pre(z);
    __syncthreads();

    for (int t = 1; t < 25; ++t) {
        float zz = bias;
#pragma unroll
        for (int k = 0; k < 32; ++k) zz = fmaf(wr[k], hist[bl][t - 1][k], zz);
        hist[bl][t][i] = tanh_pre(zz);
        __syncthreads();
    }

    // epilogue: out[b][t][o] = dot(w_out[o], hist[b][t]) + b_out[o]
    for (int e = threadIdx.x; e < 600; e += 256) {
        const int o  = e % 3;
        const int t  = (e / 3) % 25;
        const int b2 = e / 75;
        float acc = b_out[o];
#pragma unroll
        for (int k = 0; k < 32; ++k) acc = fmaf(w_out[o * 32 + k], hist[b2][t][k], acc);
        out[((size_t)(blockIdx.x * 8 + b2) * 25 + t) * 3 + o] = acc;
    }
}

extern "C" void kernel_launch(void* const* d_in, const int* in_sizes, int n_in,
                              void* d_out, int out_size, void* d_ws, size_t ws_size,
                              hipStream_t stream) {
    const float* x      = (const float*)d_in[0];
    const float* w_ih_f = (const float*)d_in[1];
    const float* w_hh_f = (const float*)d_in[2];
    const float* b_ih_f = (const float*)d_in[3];
    const float* b_hh_f = (const float*)d_in[4];
    const float* w_ih_b = (const float*)d_in[5];
    const float* w_hh_b = (const float*)d_in[6];
    const float* b_ih_b = (const float*)d_in[7];
    const float* b_hh_b = (const float*)d_in[8];
    const float* w_ih2  = (const float*)d_in[9];
    const float* w_hh2  = (const float*)d_in[10];
    const float* b_ih2  = (const float*)d_in[11];
    const float* b_hh2  = (const float*)d_in[12];
    const float* w_out  = (const float*)d_in[13];
    const float* b_out  = (const float*)d_in[14];

    float* y = (float*)d_ws;                 // [B][18] intermediate

    rnn1_kernel<<<dim3(512), dim3(256), 0, stream>>>(
        x, w_ih_f, w_hh_f, b_ih_f, b_hh_f,
        w_ih_b, w_hh_b, b_ih_b, b_hh_b, y);

    rnn2_kernel<<<dim3(RNN_B / 8), dim3(256), 0, stream>>>(
        y, w_ih2, w_hh2, b_ih2, b_hh2, w_out, b_out, (float*)d_out);
}

// Round 3
// 527.262 us; speedup vs baseline: 1.6844x; 1.5162x over previous
//
#include <hip/hip_runtime.h>

#define RNN_T 2048
#define RNN_B 4096
#define BLK 4              // timesteps per x block (20 floats = 5 float4 = 20 VGPRs)
#define NBLK (RNN_T / BLK) // 512

// tanh with pre-scaled argument: zs = 2*log2(e)*z ; tanh(z) = 1 - 2/(1 + 2^zs)
__device__ __forceinline__ float tanh_pre(float zs) {
    float e = __builtin_amdgcn_exp2f(zs);
    float r = __builtin_amdgcn_rcpf(e + 1.0f);
    return fmaf(-2.0f, r, 1.0f);
}

// Broadcast lane (group16_base | K)'s value to all 16 lanes of the group.
// ds_swizzle BitMode (5-bit masks, repeats per 32-lane half):
// src = ((lane & and) | or) ; offset = (xor<<10)|(or<<5)|and -> and=16, or=K.
template <int K>
__device__ __forceinline__ float bcast16(float v) {
    return __int_as_float(__builtin_amdgcn_ds_swizzle(__float_as_int(v), (K << 5) | 16));
}

template <int IDX>
__device__ __forceinline__ float getf(const float4 (&b)[5]) {
    constexpr int q = IDX >> 2, r = IDX & 3;
    if constexpr (r == 0) return b[q].x;
    else if constexpr (r == 1) return b[q].y;
    else if constexpr (r == 2) return b[q].z;
    else return b[q].w;
}

// One timestep: lane holds h[i]; gathers h[0..8] from lanes 0..8 of its group.
template <int U>
__device__ __forceinline__ void step16(const float4 (&buf)[5], float& h,
                                       const float (&W1)[5], const float (&W2)[9],
                                       const float bb) {
    float h0 = bcast16<0>(h), h1 = bcast16<1>(h), h2 = bcast16<2>(h);
    float h3 = bcast16<3>(h), h4 = bcast16<4>(h), h5 = bcast16<5>(h);
    float h6 = bcast16<6>(h), h7 = bcast16<7>(h), h8 = bcast16<8>(h);
    // x part (independent of broadcasts -> fills swizzle latency)
    float a0 = fmaf(W1[0], getf<U * 5 + 0>(buf), bb);
    a0 = fmaf(W1[1], getf<U * 5 + 1>(buf), a0);
    a0 = fmaf(W1[2], getf<U * 5 + 2>(buf), a0);
    a0 = fmaf(W1[3], getf<U * 5 + 3>(buf), a0);
    a0 = fmaf(W1[4], getf<U * 5 + 4>(buf), a0);
    // h part, 3 accumulators to cut dependency depth
    float a1 = W2[0] * h0;
    a1 = fmaf(W2[1], h1, a1);
    a1 = fmaf(W2[2], h2, a1);
    float a2 = W2[3] * h3;
    a2 = fmaf(W2[4], h4, a2);
    a2 = fmaf(W2[5], h5, a2);
    a0 = fmaf(W2[6], h6, a0);
    a1 = fmaf(W2[7], h7, a1);
    a2 = fmaf(W2[8], h8, a2);
    h = tanh_pre((a0 + a1) + a2);
}

__device__ __forceinline__ void loadblk(float4 (&buf)[5], const float* xp, int phys) {
    const float4* q = (const float4*)(xp + phys * (BLK * 5));
#pragma unroll
    for (int v = 0; v < 5; ++v) buf[v] = q[v];
}

template <bool FWD>
__device__ __forceinline__ void proc4(const float4 (&buf)[5], float& h,
                                      const float (&W1)[5], const float (&W2)[9],
                                      const float bb) {
    if constexpr (FWD) {
        step16<0>(buf, h, W1, W2, bb); step16<1>(buf, h, W1, W2, bb);
        step16<2>(buf, h, W1, W2, bb); step16<3>(buf, h, W1, W2, bb);
    } else {
        step16<3>(buf, h, W1, W2, bb); step16<2>(buf, h, W1, W2, bb);
        step16<1>(buf, h, W1, W2, bb); step16<0>(buf, h, W1, W2, bb);
    }
}

template <bool FWD>
__device__ __forceinline__ int physOf(int i) {
    if constexpr (FWD) return (i < NBLK - 1) ? i : (NBLK - 1);
    else { int p = NBLK - 1 - i; return (p > 0) ? p : 0; }
}

template <bool FWD>
__device__ __forceinline__ float run_chain(const float* xp, const float (&W1)[5],
                                           const float (&W2)[9], const float bb) {
    float4 A[5], B[5], C[5], D[5];   // 80 VGPRs of x buffering
    float h = 0.0f;
    loadblk(A, xp, physOf<FWD>(0));
    loadblk(B, xp, physOf<FWD>(1));
    loadblk(C, xp, physOf<FWD>(2));
#pragma unroll 1
    for (int i = 0; i < NBLK; i += 4) {
        loadblk(D, xp, physOf<FWD>(i + 3));
        proc4<FWD>(A, h, W1, W2, bb);
        loadblk(A, xp, physOf<FWD>(i + 4));
        proc4<FWD>(B, h, W1, W2, bb);
        loadblk(B, xp, physOf<FWD>(i + 5));
        proc4<FWD>(C, h, W1, W2, bb);
        loadblk(C, xp, physOf<FWD>(i + 6));
        proc4<FWD>(D, h, W1, W2, bb);
    }
    return h;
}

// 16 lanes per chain: lane i in [0,9) owns h[i]; lanes 9-15 duplicate i=8.
// 512 blocks x 256 threads = 2048 waves = 2 waves/SIMD machine-wide.
__global__ __launch_bounds__(256, 2) void rnn1_kernel(
    const float* __restrict__ x,
    const float* __restrict__ w_ih_f, const float* __restrict__ w_hh_f,
    const float* __restrict__ b_ih_f, const float* __restrict__ b_hh_f,
    const float* __restrict__ w_ih_b, const float* __restrict__ w_hh_b,
    const float* __restrict__ b_ih_b, const float* __restrict__ b_hh_b,
    float* __restrict__ y)
{
    const float SC = 2.8853900817779268f; // 2*log2(e)
    const int tid    = threadIdx.x;
    const int group  = tid >> 4;
    const int lane16 = tid & 15;
    const int chain  = blockIdx.x * 16 + group;   // 0..8191
    const int b      = chain & (RNN_B - 1);
    const int dir    = chain >> 12;               // uniform per block
    const int i      = (lane16 < 9) ? lane16 : 8;

    const float* __restrict__ wih = dir ? w_ih_b : w_ih_f;
    const float* __restrict__ whh = dir ? w_hh_b : w_hh_f;
    const float* __restrict__ bih = dir ? b_ih_b : b_ih_f;
    const float* __restrict__ bhh = dir ? b_hh_b : b_hh_f;

    float W1[5], W2[9];
#pragma unroll
    for (int d = 0; d < 5; ++d) W1[d] = wih[i * 5 + d] * SC;
#pragma unroll
    for (int k = 0; k < 9; ++k) W2[k] = whh[i * 9 + k] * SC;
    const float bb = (bih[i] + bhh[i]) * SC;

    const float* xp = x + (size_t)b * (RNN_T * 5);
    float h = dir ? run_chain<false>(xp, W1, W2, bb)
                  : run_chain<true>(xp, W1, W2, bb);

    if (lane16 < 9) y[b * 18 + dir * 9 + lane16] = h;
}

__global__ __launch_bounds__(256) void rnn2_kernel(
    const float* __restrict__ y,
    const float* __restrict__ w_ih2, const float* __restrict__ w_hh2,
    const float* __restrict__ b_ih2, const float* __restrict__ b_hh2,
    const float* __restrict__ w_out, const float* __restrict__ b_out,
    float* __restrict__ out)
{
    __shared__ float hist[8][25][32];   // 25.6 KB
    const float SC = 2.8853900817779268f;
    const int bl = threadIdx.x >> 5;    // 0..7 local batch
    const int i  = threadIdx.x & 31;    // component
    const int b  = blockIdx.x * 8 + bl;

    float wr[32];
#pragma unroll
    for (int k = 0; k < 32; ++k) wr[k] = w_hh2[i * 32 + k] * SC;
    const float bias = (b_ih2[i] + b_hh2[i]) * SC;

    // t = 0: input is y, prev hidden is 0
    const float* yb = y + b * 18;
    float z = bias;
#pragma unroll
    for (int k = 0; k < 18; ++k) z = fmaf(w_ih2[i * 18 + k] * SC, yb[k], z);
    hist[bl][0][i] = tanh_pre(z);
    __syncthreads();

    for (int t = 1; t < 25; ++t) {
        float zz = bias;
#pragma unroll
        for (int k = 0; k < 32; ++k) zz = fmaf(wr[k], hist[bl][t - 1][k], zz);
        hist[bl][t][i] = tanh_pre(zz);
        __syncthreads();
    }

    // epilogue: out[b][t][o] = dot(w_out[o], hist[b][t]) + b_out[o]
    for (int e = threadIdx.x; e < 600; e += 256) {
        const int o  = e % 3;
        const int t  = (e / 3) % 25;
        const int b2 = e / 75;
        float acc = b_out[o];
#pragma unroll
        for (int k = 0; k < 32; ++k) acc = fmaf(w_out[o * 32 + k], hist[b2][t][k], acc);
        out[((size_t)(blockIdx.x * 8 + b2) * 25 + t) * 3 + o] = acc;
    }
}

extern "C" void kernel_launch(void* const* d_in, const int* in_sizes, int n_in,
                              void* d_out, int out_size, void* d_ws, size_t ws_size,
                              hipStream_t stream) {
    const float* x      = (const float*)d_in[0];
    const float* w_ih_f = (const float*)d_in[1];
    const float* w_hh_f = (const float*)d_in[2];
    const float* b_ih_f = (const float*)d_in[3];
    const float* b_hh_f = (const float*)d_in[4];
    const float* w_ih_b = (const float*)d_in[5];
    const float* w_hh_b = (const float*)d_in[6];
    const float* b_ih_b = (const float*)d_in[7];
    const float* b_hh_b = (const float*)d_in[8];
    const float* w_ih2  = (const float*)d_in[9];
    const float* w_hh2  = (const float*)d_in[10];
    const float* b_ih2  = (const float*)d_in[11];
    const float* b_hh2  = (const float*)d_in[12];
    const float* w_out  = (const float*)d_in[13];
    const float* b_out  = (const float*)d_in[14];

    float* y = (float*)d_ws;                 // [B][18] intermediate

    rnn1_kernel<<<dim3(512), dim3(256), 0, stream>>>(
        x, w_ih_f, w_hh_f, b_ih_f, b_hh_f,
        w_ih_b, w_hh_b, b_ih_b, b_hh_b, y);

    rnn2_kernel<<<dim3(RNN_B / 8), dim3(256), 0, stream>>>(
        y, w_ih2, w_hh2, b_ih2, b_hh2, w_out, b_out, (float*)d_out);
}